// Round 2
// baseline (183.674 us; speedup 1.0000x reference)
//
#include <hip/hip_runtime.h>

#define NB 4
#define NC 128
#define NT 64
#define NHW 1024
#define QHW 256            // hw columns per k_energy block (quarter of 1024)
#define KCH 32             // fp32 k-elements staged per chunk
#define NCHUNK (QHW / KCH) // 8
#define PSTR 40            // LDS plane row stride in shorts (80 B, 16B-aligned, 2-way banks)

typedef __attribute__((ext_vector_type(8))) short short8_t;
typedef __attribute__((ext_vector_type(4))) short short4_t;
typedef __attribute__((ext_vector_type(4))) float float4_t;

// fp32 -> bf16 (RNE) bit trick; inputs are finite randn so no NaN path needed.
__device__ __forceinline__ unsigned short f2bf(float f) {
    unsigned u = __float_as_uint(f);
    return (unsigned short)((u + 0x7FFFu + ((u >> 16) & 1u)) >> 16);
}

// Convert float4 -> hi/lo bf16 planes and store 8B each.
__device__ __forceinline__ void stage4(short* H, short* L, int row, int c4, float4 v) {
    float vv[4] = {v.x, v.y, v.z, v.w};
    short4_t h, l;
    #pragma unroll
    for (int j = 0; j < 4; ++j) {
        unsigned short hb = f2bf(vv[j]);
        float hf = __uint_as_float((unsigned)hb << 16);
        h[j] = (short)hb;
        l[j] = (short)f2bf(vv[j] - hf);
    }
    *(short4_t*)(&H[row * PSTR + c4 * 4]) = h;
    *(short4_t*)(&L[row * PSTR + c4 * 4]) = l;
}

// ---------------------------------------------------------------------------
// Kernel 1: partial energy via bf16-split MFMA.
// grid = NB*NC*4; block (bc, quarter) computes
//   part[bid][t][s] = sum_{hw in quarter} x[b,c,t,hw]*y[b,c,s,hw]
// x = xh + xl (bf16 split); E ≈ xh·yh + xh·yl + xl·yh  (fp32 MFMA accum).
// Wave w owns D rows [16w,16w+16); 4 col-tiles; 12 MFMAs per chunk.
// ---------------------------------------------------------------------------
__global__ __launch_bounds__(256, 6) void k_energy(
    const float* __restrict__ x, const float* __restrict__ y,
    float* __restrict__ part)
{
    __shared__ __align__(16) short Xh[NT * PSTR], Xl[NT * PSTR];
    __shared__ __align__(16) short Yh[NT * PSTR], Yl[NT * PSTR];
    const int bc = blockIdx.x >> 2, q = blockIdx.x & 3;
    const float* xb = x + (size_t)bc * NT * NHW + q * QHW;
    const float* yb = y + (size_t)bc * NT * NHW + q * QHW;
    const int tid = threadIdx.x;
    const int lane = tid & 63, w = tid >> 6;
    const int r0 = tid >> 3, c0 = tid & 7;   // staging: rows 0..31 (+32), 8 float4/row
    const int r1 = 32 + r0;
    // fragment addresses (A: row = lane&15 within 16-tile, k = (lane>>4)*8 .. +7)
    const int frA  = (16 * w + (lane & 15)) * PSTR + (lane >> 4) * 8;
    const int frB0 = (lane & 15) * PSTR + (lane >> 4) * 8;

    float4_t acc[4];
    #pragma unroll
    for (int ct = 0; ct < 4; ++ct)
        #pragma unroll
        for (int j = 0; j < 4; ++j) acc[ct][j] = 0.f;

    const float* xp0 = xb + (size_t)r0 * NHW + c0 * 4;
    const float* xp1 = xb + (size_t)r1 * NHW + c0 * 4;
    const float* yp0 = yb + (size_t)r0 * NHW + c0 * 4;
    const float* yp1 = yb + (size_t)r1 * NHW + c0 * 4;

    float4 xv0 = *(const float4*)(xp0);
    float4 xv1 = *(const float4*)(xp1);
    float4 yv0 = *(const float4*)(yp0);
    float4 yv1 = *(const float4*)(yp1);

    for (int ch = 0; ch < NCHUNK; ++ch) {
        stage4(Xh, Xl, r0, c0, xv0);
        stage4(Xh, Xl, r1, c0, xv1);
        stage4(Yh, Yl, r0, c0, yv0);
        stage4(Yh, Yl, r1, c0, yv1);
        if (ch + 1 < NCHUNK) {        // prefetch next chunk under the MFMA phase
            int off = (ch + 1) * KCH;
            xv0 = *(const float4*)(xp0 + off);
            xv1 = *(const float4*)(xp1 + off);
            yv0 = *(const float4*)(yp0 + off);
            yv1 = *(const float4*)(yp1 + off);
        }
        __syncthreads();
        short8_t ah = *(const short8_t*)(&Xh[frA]);
        short8_t al = *(const short8_t*)(&Xl[frA]);
        #pragma unroll
        for (int ct = 0; ct < 4; ++ct) {
            short8_t bh = *(const short8_t*)(&Yh[frB0 + ct * 16 * PSTR]);
            short8_t bl = *(const short8_t*)(&Yl[frB0 + ct * 16 * PSTR]);
            acc[ct] = __builtin_amdgcn_mfma_f32_16x16x32_bf16(ah, bh, acc[ct], 0, 0, 0);
            acc[ct] = __builtin_amdgcn_mfma_f32_16x16x32_bf16(ah, bl, acc[ct], 0, 0, 0);
            acc[ct] = __builtin_amdgcn_mfma_f32_16x16x32_bf16(al, bh, acc[ct], 0, 0, 0);
        }
        __syncthreads();
    }

    // C/D layout (verified m89): col = lane&15, row = (lane>>4)*4 + reg
    float* pb = part + (size_t)blockIdx.x * (NT * NT);
    #pragma unroll
    for (int ct = 0; ct < 4; ++ct)
        #pragma unroll
        for (int r = 0; r < 4; ++r)
            pb[(16 * w + (lane >> 4) * 4 + r) * NT + 16 * ct + (lane & 15)] = acc[ct][r];
}

// ---------------------------------------------------------------------------
// Kernel 2: reduce 512 partials per (b,t,s), row-softmax of (rowmax - e).
// grid = NB*NT blocks x 256 threads; thread = (slice, s); LDS reduce; wave 0
// does the 64-wide softmax. softmax(max-e): p_s = exp(min_e - e_s), normalize.
// ---------------------------------------------------------------------------
__global__ void k_softmax(const float* __restrict__ part, float* __restrict__ att)
{
    const int b = blockIdx.x >> 6;
    const int t = blockIdx.x & 63;
    const int s = threadIdx.x & 63;
    const int sl = threadIdx.x >> 6;   // 0..3
    __shared__ float red[4][64];

    const float* p = part + (size_t)b * 512 * (NT * NT) + t * NT + s;
    float e = 0.f;
    for (int k = sl; k < 512; k += 4)
        e += p[(size_t)k * (NT * NT)];
    red[sl][s] = e;
    __syncthreads();
    if (threadIdx.x < 64) {
        e = red[0][s] + red[1][s] + red[2][s] + red[3][s];
        float mn = e;
        #pragma unroll
        for (int off = 32; off; off >>= 1) mn = fminf(mn, __shfl_xor(mn, off));
        float pv = expf(mn - e);
        float sum = pv;
        #pragma unroll
        for (int off = 32; off; off >>= 1) sum += __shfl_xor(sum, off);
        att[(size_t)blockIdx.x * NT + s] = pv / sum;
    }
}

// ---------------------------------------------------------------------------
// Kernel 3: out[b,c,t,hw] = x[b,c,t,hw] + scale * sum_s A[b,t,s]*y[b,c,s,hw]
// (unchanged from round 1 — already ~8 TB/s effective, near floor)
// ---------------------------------------------------------------------------
#define K3_SY 132
#define K3_SA 68
__global__ __launch_bounds__(256, 3) void k_out(
    const float* __restrict__ x, const float* __restrict__ y,
    const float* __restrict__ att, const float* __restrict__ scale_p,
    float* __restrict__ out)
{
    __shared__ float As[NT][K3_SA];   // As[s][t]
    __shared__ float Ys[NT][K3_SY];
    const int bc   = blockIdx.x >> 1;
    const int half = blockIdx.x & 1;
    const int b    = bc >> 7;
    const float scale = scale_p[0];
    const float* xb = x + (size_t)bc * NT * NHW + half * 512;
    const float* yb = y + (size_t)bc * NT * NHW + half * 512;
    float*       ob = out + (size_t)bc * NT * NHW + half * 512;
    const int tid = threadIdx.x;

    #pragma unroll
    for (int it = 0; it < 16; ++it) {
        int f = tid + it * 256;
        int t = f >> 6, s = f & 63;
        As[s][t] = att[((size_t)b * NT + t) * NT + s];
    }

    const int col = (tid & 31) * 4;
    const int g   = tid >> 5;

    for (int ch = 0; ch < 4; ++ch) {
        __syncthreads();
        #pragma unroll
        for (int it = 0; it < 8; ++it) {
            int f   = tid + it * 256;
            int row = f >> 5;
            int c4  = f & 31;
            *(float4*)(&Ys[row][c4 * 4]) =
                *(const float4*)(yb + (size_t)row * NHW + ch * 128 + c4 * 4);
        }
        __syncthreads();

        float4 acc[8] = {};
        #pragma unroll 4
        for (int s = 0; s < NT; ++s) {
            float4 yv = *(const float4*)(&Ys[s][col]);
            float4 al = *(const float4*)(&As[s][8 * g]);
            float4 ah = *(const float4*)(&As[s][8 * g + 4]);
            #define FMA4(A, S) \
                A.x = fmaf(S, yv.x, A.x); A.y = fmaf(S, yv.y, A.y); \
                A.z = fmaf(S, yv.z, A.z); A.w = fmaf(S, yv.w, A.w);
            FMA4(acc[0], al.x) FMA4(acc[1], al.y)
            FMA4(acc[2], al.z) FMA4(acc[3], al.w)
            FMA4(acc[4], ah.x) FMA4(acc[5], ah.y)
            FMA4(acc[6], ah.z) FMA4(acc[7], ah.w)
            #undef FMA4
        }

        #pragma unroll
        for (int r = 0; r < 8; ++r) {
            int t = 8 * g + r;
            float4 xv = *(const float4*)(xb + (size_t)t * NHW + ch * 128 + col);
            float4 o;
            o.x = fmaf(scale, acc[r].x, xv.x);
            o.y = fmaf(scale, acc[r].y, xv.y);
            o.z = fmaf(scale, acc[r].z, xv.z);
            o.w = fmaf(scale, acc[r].w, xv.w);
            *(float4*)(ob + (size_t)t * NHW + ch * 128 + col) = o;
        }
    }
}

// ---------------------------------------------------------------------------
extern "C" void kernel_launch(void* const* d_in, const int* in_sizes, int n_in,
                              void* d_out, int out_size, void* d_ws, size_t ws_size,
                              hipStream_t stream)
{
    const float* x       = (const float*)d_in[0];
    const float* y       = (const float*)d_in[1];
    const float* scale_p = (const float*)d_in[2];
    float* out = (float*)d_out;

    // Scratch: energy partials (2048 x 64 x 64 fp32 = 33.5 MB) live in d_out,
    // fully overwritten by k_out afterwards; attention (64 KB) lives in d_ws.
    float* part = out;
    float* att  = (float*)d_ws;

    k_energy <<<dim3(NB * NC * 4), 256, 0, stream>>>(x, y, part);
    k_softmax<<<dim3(NB * NT),     256, 0, stream>>>(part, att);
    k_out    <<<dim3(NB * NC * 2), 256, 0, stream>>>(x, y, att, scale_p, out);
}

// Round 3
// 178.121 us; speedup vs baseline: 1.0312x; 1.0312x over previous
//
#include <hip/hip_runtime.h>
#include <hip/hip_bf16.h>

#define NB 4
#define NC 128
#define NT 64
#define NHW 1024
#define QHW 256            // hw columns per k_energy block (quarter of 1024)
#define KCH 32             // fp32 k-elements per chunk
#define NCHUNK (QHW / KCH) // 8

typedef __attribute__((ext_vector_type(8))) short short8_t;
typedef __attribute__((ext_vector_type(4))) float float4_t;

// Split 8 fp32 into bf16 hi/lo fragments (v = hi + lo, each RNE).
__device__ __forceinline__ void cvt8(const float4& a, const float4& b,
                                     short8_t& h, short8_t& l) {
    const float vv[8] = {a.x, a.y, a.z, a.w, b.x, b.y, b.z, b.w};
    #pragma unroll
    for (int j = 0; j < 8; ++j) {
        __hip_bfloat16 hb = __float2bfloat16(vv[j]);
        float hf = __bfloat162float(hb);
        __hip_bfloat16 lb = __float2bfloat16(vv[j] - hf);
        h[j] = __builtin_bit_cast(short, hb);
        l[j] = __builtin_bit_cast(short, lb);
    }
}

// ---------------------------------------------------------------------------
// Kernel 1: partial energy, zero-LDS / zero-barrier MFMA.
// grid = NB*NC*4; block (bc, quarter): part[bid][t][s] = sum_{hw in quarter}
// x[b,c,t,hw]*y[b,c,s,hw].  E ≈ xh·yh + xh·yl + xl·yh (fp32 accum).
// Wave w owns t-rows [16w,16w+16); fragments loaded DIRECTLY from global
// (lane l&15 = row-in-tile, l>>4 = k-slab of 8 contiguous fp32).
// Depth-1 register double-buffer; ch-loop fully unrolled (static indices).
// ---------------------------------------------------------------------------
__global__ __launch_bounds__(256, 3) void k_energy(
    const float* __restrict__ x, const float* __restrict__ y,
    float* __restrict__ part)
{
    const int bc = blockIdx.x >> 2, q = blockIdx.x & 3;
    const int lane = threadIdx.x & 63, w = threadIdx.x >> 6;
    const int r = lane & 15, g = lane >> 4;
    const size_t base = (size_t)bc * NT * NHW + q * QHW;
    const float* xf = x + base + (size_t)(16 * w + r) * NHW + g * 8;
    const float* yf[4];
    #pragma unroll
    for (int ct = 0; ct < 4; ++ct)
        yf[ct] = y + base + (size_t)(16 * ct + r) * NHW + g * 8;

    float4 bufA[2][2], bufB[2][4][2];
    float4_t acc[4];
    #pragma unroll
    for (int ct = 0; ct < 4; ++ct)
        #pragma unroll
        for (int j = 0; j < 4; ++j) acc[ct][j] = 0.f;

    // prologue: chunk 0 into slot 0
    bufA[0][0] = *(const float4*)(xf);
    bufA[0][1] = *(const float4*)(xf + 4);
    #pragma unroll
    for (int ct = 0; ct < 4; ++ct) {
        bufB[0][ct][0] = *(const float4*)(yf[ct]);
        bufB[0][ct][1] = *(const float4*)(yf[ct] + 4);
    }

    #pragma unroll
    for (int ch = 0; ch < NCHUNK; ++ch) {
        const int cur = ch & 1, nxt = cur ^ 1;
        if (ch + 1 < NCHUNK) {            // issue next chunk's loads first
            const int ko = (ch + 1) * KCH;
            bufA[nxt][0] = *(const float4*)(xf + ko);
            bufA[nxt][1] = *(const float4*)(xf + ko + 4);
            #pragma unroll
            for (int ct = 0; ct < 4; ++ct) {
                bufB[nxt][ct][0] = *(const float4*)(yf[ct] + ko);
                bufB[nxt][ct][1] = *(const float4*)(yf[ct] + ko + 4);
            }
        }
        short8_t ah, al;
        cvt8(bufA[cur][0], bufA[cur][1], ah, al);
        #pragma unroll
        for (int ct = 0; ct < 4; ++ct) {
            short8_t bh, bl;
            cvt8(bufB[cur][ct][0], bufB[cur][ct][1], bh, bl);
            acc[ct] = __builtin_amdgcn_mfma_f32_16x16x32_bf16(ah, bh, acc[ct], 0, 0, 0);
            acc[ct] = __builtin_amdgcn_mfma_f32_16x16x32_bf16(ah, bl, acc[ct], 0, 0, 0);
            acc[ct] = __builtin_amdgcn_mfma_f32_16x16x32_bf16(al, bh, acc[ct], 0, 0, 0);
        }
    }

    // C/D layout (m89-verified): col = lane&15, row = (lane>>4)*4 + reg
    float* pb = part + (size_t)blockIdx.x * (NT * NT);
    #pragma unroll
    for (int ct = 0; ct < 4; ++ct)
        #pragma unroll
        for (int reg = 0; reg < 4; ++reg)
            pb[(16 * w + g * 4 + reg) * NT + 16 * ct + r] = acc[ct][reg];
}

// ---------------------------------------------------------------------------
// Kernel 2: reduce 512 partials per (b,t,s), row-softmax of (rowmax - e).
// grid = NB*NT blocks x 1024 threads (16 slices hide the strided reads).
// softmax(max-e) stabilized: p_s = exp(min_e - e_s), normalize.
// ---------------------------------------------------------------------------
__global__ void k_softmax(const float* __restrict__ part, float* __restrict__ att)
{
    const int b = blockIdx.x >> 6;
    const int t = blockIdx.x & 63;
    const int s = threadIdx.x & 63;
    const int sl = threadIdx.x >> 6;   // 0..15
    __shared__ float red[16][64];

    const float* p = part + (size_t)b * 512 * (NT * NT) + t * NT + s;
    float e = 0.f;
    #pragma unroll 8
    for (int k = sl; k < 512; k += 16)
        e += p[(size_t)k * (NT * NT)];
    red[sl][s] = e;
    __syncthreads();
    if (threadIdx.x < 64) {
        e = 0.f;
        #pragma unroll
        for (int i = 0; i < 16; ++i) e += red[i][s];
        float mn = e;
        #pragma unroll
        for (int off = 32; off; off >>= 1) mn = fminf(mn, __shfl_xor(mn, off));
        float pv = expf(mn - e);
        float sum = pv;
        #pragma unroll
        for (int off = 32; off; off >>= 1) sum += __shfl_xor(sum, off);
        att[(size_t)blockIdx.x * NT + s] = pv / sum;
    }
}

// ---------------------------------------------------------------------------
// Kernel 3: out[b,c,t,hw] = x[b,c,t,hw] + scale * sum_s A[b,t,s]*y[b,c,s,hw]
// (unchanged — already near its 402 MB HBM floor)
// ---------------------------------------------------------------------------
#define K3_SY 132
#define K3_SA 68
__global__ __launch_bounds__(256, 3) void k_out(
    const float* __restrict__ x, const float* __restrict__ y,
    const float* __restrict__ att, const float* __restrict__ scale_p,
    float* __restrict__ out)
{
    __shared__ float As[NT][K3_SA];   // As[s][t]
    __shared__ float Ys[NT][K3_SY];
    const int bc   = blockIdx.x >> 1;
    const int half = blockIdx.x & 1;
    const int b    = bc >> 7;
    const float scale = scale_p[0];
    const float* xb = x + (size_t)bc * NT * NHW + half * 512;
    const float* yb = y + (size_t)bc * NT * NHW + half * 512;
    float*       ob = out + (size_t)bc * NT * NHW + half * 512;
    const int tid = threadIdx.x;

    #pragma unroll
    for (int it = 0; it < 16; ++it) {
        int f = tid + it * 256;
        int t = f >> 6, s = f & 63;
        As[s][t] = att[((size_t)b * NT + t) * NT + s];
    }

    const int col = (tid & 31) * 4;
    const int g   = tid >> 5;

    for (int ch = 0; ch < 4; ++ch) {
        __syncthreads();
        #pragma unroll
        for (int it = 0; it < 8; ++it) {
            int f   = tid + it * 256;
            int row = f >> 5;
            int c4  = f & 31;
            *(float4*)(&Ys[row][c4 * 4]) =
                *(const float4*)(yb + (size_t)row * NHW + ch * 128 + c4 * 4);
        }
        __syncthreads();

        float4 acc[8] = {};
        #pragma unroll 4
        for (int s = 0; s < NT; ++s) {
            float4 yv = *(const float4*)(&Ys[s][col]);
            float4 al = *(const float4*)(&As[s][8 * g]);
            float4 ah = *(const float4*)(&As[s][8 * g + 4]);
            #define FMA4(A, S) \
                A.x = fmaf(S, yv.x, A.x); A.y = fmaf(S, yv.y, A.y); \
                A.z = fmaf(S, yv.z, A.z); A.w = fmaf(S, yv.w, A.w);
            FMA4(acc[0], al.x) FMA4(acc[1], al.y)
            FMA4(acc[2], al.z) FMA4(acc[3], al.w)
            FMA4(acc[4], ah.x) FMA4(acc[5], ah.y)
            FMA4(acc[6], ah.z) FMA4(acc[7], ah.w)
            #undef FMA4
        }

        #pragma unroll
        for (int rr = 0; rr < 8; ++rr) {
            int t = 8 * g + rr;
            float4 xv = *(const float4*)(xb + (size_t)t * NHW + ch * 128 + col);
            float4 o;
            o.x = fmaf(scale, acc[rr].x, xv.x);
            o.y = fmaf(scale, acc[rr].y, xv.y);
            o.z = fmaf(scale, acc[rr].z, xv.z);
            o.w = fmaf(scale, acc[rr].w, xv.w);
            *(float4*)(ob + (size_t)t * NHW + ch * 128 + col) = o;
        }
    }
}

// ---------------------------------------------------------------------------
extern "C" void kernel_launch(void* const* d_in, const int* in_sizes, int n_in,
                              void* d_out, int out_size, void* d_ws, size_t ws_size,
                              hipStream_t stream)
{
    const float* x       = (const float*)d_in[0];
    const float* y       = (const float*)d_in[1];
    const float* scale_p = (const float*)d_in[2];
    float* out = (float*)d_out;

    // Scratch: energy partials (2048 x 64 x 64 fp32 = 33.5 MB) live in d_out,
    // fully overwritten by k_out afterwards; attention (64 KB) lives in d_ws.
    float* part = out;
    float* att  = (float*)d_ws;

    k_energy <<<dim3(NB * NC * 4),  256, 0, stream>>>(x, y, part);
    k_softmax<<<dim3(NB * NT),     1024, 0, stream>>>(part, att);
    k_out    <<<dim3(NB * NC * 2),  256, 0, stream>>>(x, y, att, scale_p, out);
}

// Round 4
// 154.730 us; speedup vs baseline: 1.1871x; 1.1512x over previous
//
#include <hip/hip_runtime.h>
#include <hip/hip_bf16.h>

#define NB 4
#define NC 128
#define NT 64
#define NHW 1024
#define QHW 256            // hw columns per k_energy block (quarter of 1024)
#define KCH 32             // fp32 k-elements per chunk
#define NCHUNK (QHW / KCH) // 8

typedef __attribute__((ext_vector_type(8))) short short8_t;
typedef __attribute__((ext_vector_type(4))) float float4_t;
typedef const unsigned __attribute__((address_space(1)))* gas_t;
typedef unsigned __attribute__((address_space(3)))* las_t;

// Split 8 fp32 (two float4) into bf16 hi/lo fragments (v = hi + lo, RNE).
__device__ __forceinline__ void cvt8(const float4& a, const float4& b,
                                     short8_t& h, short8_t& l) {
    const float vv[8] = {a.x, a.y, a.z, a.w, b.x, b.y, b.z, b.w};
    #pragma unroll
    for (int j = 0; j < 8; ++j) {
        __hip_bfloat16 hb = __float2bfloat16(vv[j]);
        float hf = __bfloat162float(hb);
        __hip_bfloat16 lb = __float2bfloat16(vv[j] - hf);
        h[j] = __builtin_bit_cast(short, hb);
        l[j] = __builtin_bit_cast(short, lb);
    }
}

// ---------------------------------------------------------------------------
// Kernel 1: partial energy — m97-style pipeline.
// grid = NB*NC*4; block (bc, quarter): part[bid][t][s] = sum_{hw in quarter}
// x[b,c,t,hw]*y[b,c,s,hw].  E ≈ xh·yh + xh·yl + xl·yh (fp32 MFMA accum).
// global_load_lds (16B) -> double-buffered LDS, ONE barrier per chunk,
// stage(next) issued before compute(cur). LDS is XOR-swizzled via the
// pre-swizzled GLOBAL source (rule #21): LDS[row][u] = G[row][u ^ (row&7)]
// (u = 16B unit, 8 per 32-float row), read back with the same XOR ->
// fragment ds_read_b128 spreads 8 rows over 8 bank-quads (2-way = free).
// ---------------------------------------------------------------------------
__global__ __launch_bounds__(256, 5) void k_energy(
    const float* __restrict__ x, const float* __restrict__ y,
    float* __restrict__ part)
{
    __shared__ float4 Xs[2][NT][8];   // [buf][row][unit]  8KB per buf per side
    __shared__ float4 Ys[2][NT][8];
    const int bc = blockIdx.x >> 2, q = blockIdx.x & 3;
    const float* xb = x + (size_t)bc * NT * NHW + q * QHW;
    const float* yb = y + (size_t)bc * NT * NHW + q * QHW;
    const int lane = threadIdx.x & 63, w = threadIdx.x >> 6;
    const int r = lane & 15, g = lane >> 4;

    // staging geometry: wave w, issue i stages rows [16w+8i, 16w+8i+8)
    const int sr = (lane >> 3);       // row-in-group 0..7
    const int su = lane & 7;          // dest 16B unit

    #define STAGE(pb, ch)                                                     \
        _Pragma("unroll")                                                     \
        for (int i = 0; i < 2; ++i) {                                         \
            const int row = 16 * w + 8 * i + sr;                              \
            const int uu  = su ^ (row & 7);                                   \
            __builtin_amdgcn_global_load_lds(                                 \
                (gas_t)(xb + (size_t)row * NHW + (ch) * KCH + uu * 4),        \
                (las_t)&Xs[pb][16 * w + 8 * i][0], 16, 0, 0);                 \
            __builtin_amdgcn_global_load_lds(                                 \
                (gas_t)(yb + (size_t)row * NHW + (ch) * KCH + uu * 4),        \
                (las_t)&Ys[pb][16 * w + 8 * i][0], 16, 0, 0);                 \
        }

    float4_t acc[4];
    #pragma unroll
    for (int ct = 0; ct < 4; ++ct)
        #pragma unroll
        for (int j = 0; j < 4; ++j) acc[ct][j] = 0.f;

    STAGE(0, 0);
    __syncthreads();                  // drains vmcnt(0): buf0 ready

    const int u0 = (2 * g)     ^ (r & 7);   // (16w+r)&7 == r&7
    const int u1 = (2 * g + 1) ^ (r & 7);

    #pragma unroll 2
    for (int ch = 0; ch < NCHUNK; ++ch) {
        const int pb = ch & 1;
        if (ch + 1 < NCHUNK) STAGE(pb ^ 1, ch + 1);   // fire-and-forget DMA

        short8_t ah, al;
        cvt8(Xs[pb][16 * w + r][u0], Xs[pb][16 * w + r][u1], ah, al);
        #pragma unroll
        for (int ct = 0; ct < 4; ++ct) {
            short8_t bh, bl;
            cvt8(Ys[pb][16 * ct + r][u0], Ys[pb][16 * ct + r][u1], bh, bl);
            acc[ct] = __builtin_amdgcn_mfma_f32_16x16x32_bf16(ah, bh, acc[ct], 0, 0, 0);
            acc[ct] = __builtin_amdgcn_mfma_f32_16x16x32_bf16(ah, bl, acc[ct], 0, 0, 0);
            acc[ct] = __builtin_amdgcn_mfma_f32_16x16x32_bf16(al, bh, acc[ct], 0, 0, 0);
        }
        __syncthreads();              // next buf staged; cur buf free for ch+2
    }
    #undef STAGE

    // C/D layout (m89-verified): col = lane&15, row = (lane>>4)*4 + reg
    float* pb_out = part + (size_t)blockIdx.x * (NT * NT);
    #pragma unroll
    for (int ct = 0; ct < 4; ++ct)
        #pragma unroll
        for (int reg = 0; reg < 4; ++reg)
            pb_out[(16 * w + g * 4 + reg) * NT + 16 * ct + r] = acc[ct][reg];
}

// ---------------------------------------------------------------------------
// Kernel 2: reduce 512 partials per (b,t,s), row-softmax of (rowmax - e).
// grid = NB*NT blocks x 1024 threads (16 slices hide the strided reads).
// softmax(max-e) stabilized: p_s = exp(min_e - e_s), normalize.
// ---------------------------------------------------------------------------
__global__ void k_softmax(const float* __restrict__ part, float* __restrict__ att)
{
    const int b = blockIdx.x >> 6;
    const int t = blockIdx.x & 63;
    const int s = threadIdx.x & 63;
    const int sl = threadIdx.x >> 6;   // 0..15
    __shared__ float red[16][64];

    const float* p = part + (size_t)b * 512 * (NT * NT) + t * NT + s;
    float e = 0.f;
    #pragma unroll 8
    for (int k = sl; k < 512; k += 16)
        e += p[(size_t)k * (NT * NT)];
    red[sl][s] = e;
    __syncthreads();
    if (threadIdx.x < 64) {
        e = 0.f;
        #pragma unroll
        for (int i = 0; i < 16; ++i) e += red[i][s];
        float mn = e;
        #pragma unroll
        for (int off = 32; off; off >>= 1) mn = fminf(mn, __shfl_xor(mn, off));
        float pv = expf(mn - e);
        float sum = pv;
        #pragma unroll
        for (int off = 32; off; off >>= 1) sum += __shfl_xor(sum, off);
        att[(size_t)blockIdx.x * NT + s] = pv / sum;
    }
}

// ---------------------------------------------------------------------------
// Kernel 3: out[b,c,t,hw] = x[b,c,t,hw] + scale * sum_s A[b,t,s]*y[b,c,s,hw]
// (unchanged — ~7 TB/s effective, near floor)
// ---------------------------------------------------------------------------
#define K3_SY 132
#define K3_SA 68
__global__ __launch_bounds__(256, 3) void k_out(
    const float* __restrict__ x, const float* __restrict__ y,
    const float* __restrict__ att, const float* __restrict__ scale_p,
    float* __restrict__ out)
{
    __shared__ float As[NT][K3_SA];   // As[s][t]
    __shared__ float Ys[NT][K3_SY];
    const int bc   = blockIdx.x >> 1;
    const int half = blockIdx.x & 1;
    const int b    = bc >> 7;
    const float scale = scale_p[0];
    const float* xb = x + (size_t)bc * NT * NHW + half * 512;
    const float* yb = y + (size_t)bc * NT * NHW + half * 512;
    float*       ob = out + (size_t)bc * NT * NHW + half * 512;
    const int tid = threadIdx.x;

    #pragma unroll
    for (int it = 0; it < 16; ++it) {
        int f = tid + it * 256;
        int t = f >> 6, s = f & 63;
        As[s][t] = att[((size_t)b * NT + t) * NT + s];
    }

    const int col = (tid & 31) * 4;
    const int g   = tid >> 5;

    for (int ch = 0; ch < 4; ++ch) {
        __syncthreads();
        #pragma unroll
        for (int it = 0; it < 8; ++it) {
            int f   = tid + it * 256;
            int row = f >> 5;
            int c4  = f & 31;
            *(float4*)(&Ys[row][c4 * 4]) =
                *(const float4*)(yb + (size_t)row * NHW + ch * 128 + c4 * 4);
        }
        __syncthreads();

        float4 acc[8] = {};
        #pragma unroll 4
        for (int s = 0; s < NT; ++s) {
            float4 yv = *(const float4*)(&Ys[s][col]);
            float4 al = *(const float4*)(&As[s][8 * g]);
            float4 ah = *(const float4*)(&As[s][8 * g + 4]);
            #define FMA4(A, S) \
                A.x = fmaf(S, yv.x, A.x); A.y = fmaf(S, yv.y, A.y); \
                A.z = fmaf(S, yv.z, A.z); A.w = fmaf(S, yv.w, A.w);
            FMA4(acc[0], al.x) FMA4(acc[1], al.y)
            FMA4(acc[2], al.z) FMA4(acc[3], al.w)
            FMA4(acc[4], ah.x) FMA4(acc[5], ah.y)
            FMA4(acc[6], ah.z) FMA4(acc[7], ah.w)
            #undef FMA4
        }

        #pragma unroll
        for (int rr = 0; rr < 8; ++rr) {
            int t = 8 * g + rr;
            float4 xv = *(const float4*)(xb + (size_t)t * NHW + ch * 128 + col);
            float4 o;
            o.x = fmaf(scale, acc[rr].x, xv.x);
            o.y = fmaf(scale, acc[rr].y, xv.y);
            o.z = fmaf(scale, acc[rr].z, xv.z);
            o.w = fmaf(scale, acc[rr].w, xv.w);
            *(float4*)(ob + (size_t)t * NHW + ch * 128 + col) = o;
        }
    }
}

// ---------------------------------------------------------------------------
extern "C" void kernel_launch(void* const* d_in, const int* in_sizes, int n_in,
                              void* d_out, int out_size, void* d_ws, size_t ws_size,
                              hipStream_t stream)
{
    const float* x       = (const float*)d_in[0];
    const float* y       = (const float*)d_in[1];
    const float* scale_p = (const float*)d_in[2];
    float* out = (float*)d_out;

    // Scratch: energy partials (2048 x 64 x 64 fp32 = 33.5 MB) live in d_out,
    // fully overwritten by k_out afterwards; attention (64 KB) lives in d_ws.
    float* part = out;
    float* att  = (float*)d_ws;

    k_energy <<<dim3(NB * NC * 4),  256, 0, stream>>>(x, y, part);
    k_softmax<<<dim3(NB * NT),     1024, 0, stream>>>(part, att);
    k_out    <<<dim3(NB * NC * 2),  256, 0, stream>>>(x, y, att, scale_p, out);
}